// Round 12
// baseline (357.258 us; speedup 1.0000x reference)
//
#include <hip/hip_runtime.h>
#include <hip/hip_bf16.h>

#define N_IN  128
#define N_OUT 64
#define CFB    256          // nodes per coarse bucket
#define MAXNBC 200          // >= ceil(50000/256) = 196
#define SLACKC 5120         // slots per coarse bucket (mean 4096)
#define CHUNK  2048         // edges per fill chunk
#define PADR   136          // LDS row pitch in bf16 (+8 pad -> 2-way banks, free)

typedef __attribute__((ext_vector_type(8))) short short8;
typedef __attribute__((ext_vector_type(4))) float floatx4;
typedef __attribute__((ext_vector_type(2))) float floatx2;

__device__ __forceinline__ unsigned pack_bf16(float a, float b) {
    __hip_bfloat16 ba = __float2bfloat16(a);
    __hip_bfloat16 bb = __float2bfloat16(b);
    unsigned short ua = *(unsigned short*)&ba;
    unsigned short ub = *(unsigned short*)&bb;
    return ((unsigned)ub << 16) | ua;
}
__device__ __forceinline__ unsigned char fp8b(float v) {
    return (unsigned char)(__builtin_amdgcn_cvt_pk_fp8_f32(v, v, 0, false) & 0xff);
}

// Device-scope tree grid-barrier. bar[0..7] sub-counters, bar[8] root,
// bar[9] generation. All zeroed by the host-side memset. Requires all G
// blocks co-resident (G = occupancy-query * CUs). Atomics are device-scope
// (cross-XCD safe); spins use agent-scope atomic loads (no RMW storm).
__device__ __forceinline__ void grid_barrier(int* bar, int G) {
    __syncthreads();
    if (threadIdx.x == 0) {
        __threadfence();
        int gen = __hip_atomic_load(&bar[9], __ATOMIC_RELAXED, __HIP_MEMORY_SCOPE_AGENT);
        int sub = blockIdx.x & 7;
        int subn = (G >> 3) + ((sub < (G & 7)) ? 1 : 0);
        bool release = false;
        if (atomicAdd(&bar[sub], 1) == subn - 1) {
            atomicExch(&bar[sub], 0);
            if (atomicAdd(&bar[8], 1) == 7) {
                atomicExch(&bar[8], 0);
                __threadfence();
                atomicAdd(&bar[9], 1);
                release = true;
            }
        }
        if (!release) {
            while (__hip_atomic_load(&bar[9], __ATOMIC_ACQUIRE,
                                     __HIP_MEMORY_SCOPE_AGENT) == gen)
                __builtin_amdgcn_s_sleep(8);
        }
        __threadfence();
    }
    __syncthreads();
}

// One persistent-block kernel, 3 phases over 2 grid barriers:
// P1 fill (+CT fold on 64 tail blocks) -> P2 sort||gemm -> P3 gather.
__global__ __launch_bounds__(256, 3) void fused_kernel(
        const int* __restrict__ ei,
        int* __restrict__ gcur,           // NBC relative cursors (zeroed)
        int* __restrict__ bar,            // 10 ints (zeroed)
        unsigned* __restrict__ gsorted,
        const float* __restrict__ W0, const float* __restrict__ W1,
        const float* __restrict__ W2, const float* __restrict__ Wfc,
        __hip_bfloat16* __restrict__ CT,
        unsigned short* __restrict__ srow,
        int* __restrict__ offs, int* __restrict__ cnt, float* __restrict__ dis,
        const float* __restrict__ x,
        float* __restrict__ out, unsigned char* __restrict__ z8,
        int E, int N, int NBC, int NCH, int GB, int G) {
    __shared__ __align__(16) char smem[(64 + 128) * PADR * 2];   // 52224 B union
    int tid = threadIdx.x;

    // ================= P1: fill + CT =================
    for (int ch = blockIdx.x; ch < NCH; ch += G) {
        int* lcnt = (int*)smem;
        int* gbase_s = lcnt + MAXNBC;
        int base = ch * CHUNK;
        for (int i = tid; i < NBC; i += 256) lcnt[i] = 0;
        __syncthreads();
        int myc[CHUNK / 256];
        #pragma unroll
        for (int q = 0; q < CHUNK / 256; ++q) {
            int e = base + q * 256 + tid;
            int c = (e < E) ? ei[E + e] : -1;
            myc[q] = c;
            if (c >= 0) atomicAdd(&lcnt[c >> 8], 1);
        }
        __syncthreads();
        for (int f = tid; f < NBC; f += 256) {
            int n = lcnt[f];
            gbase_s[f] = (n > 0) ? (f * SLACKC + atomicAdd(&gcur[f], n)) : 0;
        }
        __syncthreads();
        #pragma unroll
        for (int q = 0; q < CHUNK / 256; ++q) {
            int c = myc[q];
            if (c >= 0) {
                int e = base + q * 256 + tid;
                unsigned r = (unsigned)ei[e];
                int p = atomicAdd(&gbase_s[c >> 8], 1);
                if (p < ((c >> 8) + 1) * SLACKC)   // overflow guard (P ~ 0)
                    gsorted[p] = ((unsigned)c << 16) | r;
            }
        }
        __syncthreads();
    }
    if ((int)blockIdx.x >= G - 64) {      // CT fold on idle tail blocks
        int t = ((int)blockIdx.x - (G - 64)) * 256 + tid;
        int n = t >> 7;
        int i = t & 127;
        float a = 0.f;
        if (n < 64) {
            for (int k = 0; k < 128; ++k)
                a += Wfc[n * 384 + k] * W0[k * N_IN + i];
        } else {
            int o = n - 64;
            for (int k = 0; k < 128; ++k)
                a += Wfc[o * 384 + 128 + k] * W1[k * N_IN + i]
                   + Wfc[o * 384 + 256 + k] * W2[k * N_IN + i];
        }
        CT[t] = __float2bfloat16(a);
    }
    grid_barrier(bar, G);

    // ================= P2: sort || gemm =================
    for (int u = blockIdx.x; u < NBC + GB; u += G) {
        if (u < NBC) {
            // per-coarse-bucket counting sort -> exact CSR (int LDS atomics
            // only; f32 LDS atomicAdd is a CAS loop -- R5 lesson)
            unsigned* ev = (unsigned*)smem;            // up to SLACKC (20KB)
            int* c256 = (int*)(smem + SLACKC * 4);
            int* cur  = c256 + 256;
            int* ts   = cur + 256;
            int f = u;
            int lo = f * SLACKC;
            int m = min(gcur[f], SLACKC);
            for (int i = tid; i < m; i += 256) ev[i] = gsorted[lo + i];
            c256[tid] = 0;
            __syncthreads();
            for (int i = tid; i < m; i += 256)
                atomicAdd(&c256[(ev[i] >> 16) & (CFB - 1)], 1);
            __syncthreads();
            int v = c256[tid];
            int xx = v;
            ts[tid] = xx;
            __syncthreads();
            for (int off = 1; off < 256; off <<= 1) {
                int t2 = (tid >= off) ? ts[tid - off] : 0;
                __syncthreads();
                xx += t2; ts[tid] = xx;
                __syncthreads();
            }
            int b = xx - v;
            cur[tid] = b;
            int node = f * CFB + tid;
            if (node < N) {
                offs[node] = lo + b;
                cnt[node] = v;
                dis[node] = v > 0 ? rsqrtf((float)v) : 0.f;
            }
            __syncthreads();
            for (int i = tid; i < m; i += 256) {
                unsigned val = ev[i];
                int cl = (val >> 16) & (CFB - 1);
                int p = atomicAdd(&cur[cl], 1);
                srow[lo + p] = (unsigned short)(val & 0xffffu);
            }
        } else {
            // MFMA gemm tile: out = x@C0^T, z8 = fp8(x@C12^T) unscaled
            unsigned short* xs = (unsigned short*)smem;
            unsigned short* Bs = xs + 64 * PADR;
            int base = (u - NBC) * 64;
            {
                int row = tid >> 2;
                int colq = (tid & 3) * 32;
                int node = base + row;
                unsigned tmp[16];
                if (node < N) {
                    const float4* src = (const float4*)(x + (size_t)node * N_IN + colq);
                    #pragma unroll
                    for (int q = 0; q < 8; ++q) {
                        float4 vv = src[q];
                        tmp[q * 2]     = pack_bf16(vv.x, vv.y);
                        tmp[q * 2 + 1] = pack_bf16(vv.z, vv.w);
                    }
                } else {
                    #pragma unroll
                    for (int q = 0; q < 16; ++q) tmp[q] = 0u;
                }
                unsigned* dst = (unsigned*)(xs + row * PADR + colq);
                #pragma unroll
                for (int q = 0; q < 16; ++q) dst[q] = tmp[q];
            }
            {
                const unsigned* src = (const unsigned*)CT;
                for (int c = tid; c < 8192; c += 256) {
                    int row = c >> 6;
                    int col = (c & 63) * 2;
                    *(unsigned*)(Bs + row * PADR + col) = src[c];
                }
            }
            __syncthreads();

            int wave = tid >> 6, lane = tid & 63;
            int wm = wave & 1, wn = wave >> 1;
            int quad = lane >> 4, l16 = lane & 15;

            floatx4 acc[2][4];
            #pragma unroll
            for (int mt = 0; mt < 2; ++mt)
                #pragma unroll
                for (int nt = 0; nt < 4; ++nt)
                    acc[mt][nt] = (floatx4){0.f, 0.f, 0.f, 0.f};

            #pragma unroll
            for (int kc = 0; kc < 4; ++kc) {
                int kof = kc * 32 + quad * 8;
                short8 afr[2], bfr[4];
                #pragma unroll
                for (int mt = 0; mt < 2; ++mt)
                    afr[mt] = *(const short8*)(xs + (wm * 32 + mt * 16 + l16) * PADR + kof);
                #pragma unroll
                for (int nt = 0; nt < 4; ++nt)
                    bfr[nt] = *(const short8*)(Bs + (wn * 64 + nt * 16 + l16) * PADR + kof);
                #pragma unroll
                for (int mt = 0; mt < 2; ++mt)
                    #pragma unroll
                    for (int nt = 0; nt < 4; ++nt)
                        acc[mt][nt] = __builtin_amdgcn_mfma_f32_16x16x32_bf16(
                            afr[mt], bfr[nt], acc[mt][nt], 0, 0, 0);
            }

            #pragma unroll
            for (int mt = 0; mt < 2; ++mt) {
                #pragma unroll
                for (int reg = 0; reg < 4; ++reg) {
                    int node = base + wm * 32 + mt * 16 + quad * 4 + reg;
                    if (node >= N) continue;
                    if (wn == 0) {
                        #pragma unroll
                        for (int nt = 0; nt < 4; ++nt)
                            out[(size_t)node * N_OUT + nt * 16 + l16] = acc[mt][nt][reg];
                    } else {
                        #pragma unroll
                        for (int nt = 0; nt < 4; ++nt)
                            z8[((size_t)node << 6) + nt * 16 + l16] = fp8b(acc[mt][nt][reg]);
                    }
                }
            }
        }
        __syncthreads();
    }
    grid_barrier(bar, G);

    // ================= P3: gather =================
    int ngrp = (N + 3) >> 2;
    int lane = tid & 63;
    int sub  = lane >> 3;
    int jj   = lane & 7;
    for (int g = blockIdx.x; g < ngrp; g += G) {
        int node = g * 4 + (tid >> 6);
        if (node >= N) continue;
        int start = offs[node];
        int deg   = cnt[node];
        float a[8] = {0.f, 0.f, 0.f, 0.f, 0.f, 0.f, 0.f, 0.f};
        for (int k0 = 0; k0 < deg; k0 += 64) {
            int m = min(64, deg - k0);
            int idx = 0; float dv = 0.f;
            if (lane < m) {
                idx = (int)srow[start + k0 + lane];
                dv = dis[idx];
            }
            for (int kk = 0; kk < m; kk += 16) {
                int s0 = kk + sub, s1 = kk + 8 + sub;
                int r0 = __shfl(idx, s0); float d0 = __shfl(dv, s0);
                int r1 = __shfl(idx, s1); float d1 = __shfl(dv, s1);
                uint2 u0 = make_uint2(0u, 0u), u1 = make_uint2(0u, 0u);
                if (s0 < m) u0 = *(const uint2*)(z8 + ((size_t)r0 << 6) + jj * 8);
                if (s1 < m) u1 = *(const uint2*)(z8 + ((size_t)r1 << 6) + jj * 8);
                floatx2 p00 = __builtin_amdgcn_cvt_pk_f32_fp8(u0.x, false);
                floatx2 p01 = __builtin_amdgcn_cvt_pk_f32_fp8(u0.x, true);
                floatx2 p02 = __builtin_amdgcn_cvt_pk_f32_fp8(u0.y, false);
                floatx2 p03 = __builtin_amdgcn_cvt_pk_f32_fp8(u0.y, true);
                floatx2 p10 = __builtin_amdgcn_cvt_pk_f32_fp8(u1.x, false);
                floatx2 p11 = __builtin_amdgcn_cvt_pk_f32_fp8(u1.x, true);
                floatx2 p12 = __builtin_amdgcn_cvt_pk_f32_fp8(u1.y, false);
                floatx2 p13 = __builtin_amdgcn_cvt_pk_f32_fp8(u1.y, true);
                a[0] += d0 * p00.x + d1 * p10.x;
                a[1] += d0 * p00.y + d1 * p10.y;
                a[2] += d0 * p01.x + d1 * p11.x;
                a[3] += d0 * p01.y + d1 * p11.y;
                a[4] += d0 * p02.x + d1 * p12.x;
                a[5] += d0 * p02.y + d1 * p12.y;
                a[6] += d0 * p03.x + d1 * p13.x;
                a[7] += d0 * p03.y + d1 * p13.y;
            }
        }
        #pragma unroll
        for (int q = 0; q < 8; ++q) {
            a[q] += __shfl_xor(a[q], 8);
            a[q] += __shfl_xor(a[q], 16);
            a[q] += __shfl_xor(a[q], 32);
        }
        if (lane < 8 && deg > 0) {
            float dn = dis[node];
            float4* op = (float4*)(out + ((size_t)node << 6) + jj * 8);
            float4 o0 = op[0], o1 = op[1];
            o0.x += dn * a[0]; o0.y += dn * a[1]; o0.z += dn * a[2]; o0.w += dn * a[3];
            o1.x += dn * a[4]; o1.y += dn * a[5]; o1.z += dn * a[6]; o1.w += dn * a[7];
            op[0] = o0; op[1] = o1;
        }
    }
}

extern "C" void kernel_launch(void* const* d_in, const int* in_sizes, int n_in,
                              void* d_out, int out_size, void* d_ws, size_t ws_size,
                              hipStream_t stream) {
    const float* x   = (const float*)d_in[0];
    const int*   ei  = (const int*)d_in[1];
    const float* W0  = (const float*)d_in[2];
    const float* W1  = (const float*)d_in[3];
    const float* W2  = (const float*)d_in[4];
    const float* Wfc = (const float*)d_in[5];
    float* out = (float*)d_out;
    int N = in_sizes[0] / N_IN;
    int E = in_sizes[1] / 2;
    int NBC = (N + CFB - 1) / CFB;        // 196
    int NCH = (E + CHUNK - 1) / CHUNK;    // 391
    int GB  = (N + 63) / 64;              // 782

    __hip_bfloat16* CT = (__hip_bfloat16*)d_ws;             // 32 KB
    int*   cnt  = (int*)((char*)d_ws + 32768);              // N
    float* dis  = (float*)(cnt + N);                        // N
    int*   gcur = (int*)(dis + N);                          // NBC (zeroed)
    int*   bar  = gcur + NBC;                               // 16  (zeroed)
    int*   offs = bar + 16;                                 // N
    unsigned* gsorted = (unsigned*)(offs + N);              // NBC*SLACKC
    unsigned short* srow = (unsigned short*)(gsorted + (size_t)NBC * SLACKC);
    size_t zoff = ((size_t)(srow + (size_t)NBC * SLACKC) - (size_t)d_ws + 63) & ~(size_t)63;
    unsigned char* z8 = (unsigned char*)d_ws + zoff;        // N*64 fp8

    // co-resident grid: occupancy query (host-side, capture-safe, deterministic)
    int occ = 0;
    if (hipOccupancyMaxActiveBlocksPerMultiprocessor(
            &occ, (const void*)fused_kernel, 256, 0) != hipSuccess || occ < 1)
        occ = 2;
    int G = occ * 256;                    // 256 CUs on MI355X

    hipMemsetAsync(gcur, 0, (size_t)(NBC + 16) * sizeof(int), stream);
    fused_kernel<<<G, 256, 0, stream>>>(ei, gcur, bar, gsorted,
                                        W0, W1, W2, Wfc, CT,
                                        srow, offs, cnt, dis,
                                        x, out, z8,
                                        E, N, NBC, NCH, GB, G);
}

// Round 13
// 144.452 us; speedup vs baseline: 2.4732x; 2.4732x over previous
//
#include <hip/hip_runtime.h>
#include <hip/hip_bf16.h>

#define N_IN  128
#define N_OUT 64
#define CFB    256          // nodes per coarse bucket (fill/sort granularity)
#define MAXNBC 200          // >= ceil(50000/256) = 196
#define SLACKC 5120         // slots per coarse bucket (mean 4096, +16 sigma)
#define CHUNK  2048         // edges per fill block (391 blocks)
#define PADR   136          // LDS row pitch in bf16 (+8 pad -> 2-way banks, free)

typedef __attribute__((ext_vector_type(8))) short short8;
typedef __attribute__((ext_vector_type(4))) float floatx4;
typedef __attribute__((ext_vector_type(2))) float floatx2;

__device__ __forceinline__ unsigned pack_bf16(float a, float b) {
    __hip_bfloat16 ba = __float2bfloat16(a);
    __hip_bfloat16 bb = __float2bfloat16(b);
    unsigned short ua = *(unsigned short*)&ba;
    unsigned short ub = *(unsigned short*)&bb;
    return ((unsigned)ub << 16) | ua;
}
// f32 -> OCP e4m3 byte (gfx950 cvt_pk_fp8 is OCP-format)
__device__ __forceinline__ unsigned char fp8b(float v) {
    return (unsigned char)(__builtin_amdgcn_cvt_pk_fp8_f32(v, v, 0, false) & 0xff);
}

// Append edges into per-coarse-bucket slack regions (relative cursors; gcur
// zeroed by memset). Runs average CHUNK/NBC ~ 10.5 edges -> writes mostly
// cover cache lines (R4/R9 lesson: isolated sub-line stores cost 64B each).
// Blocks 0..63 additionally compute the folded weights CT[128][128] bf16
// (rows 0..63 = out cols Wfc[:,:128]@W0; 64..127 = z cols W1,W2 branches) --
// CT is consumed only by the NEXT dispatch, so overlapping it here is free.
__global__ __launch_bounds__(256) void fill_scatter(const int* __restrict__ ei,
                                                    int* __restrict__ gcur,
                                                    unsigned* __restrict__ gsorted,
                                                    const float* __restrict__ W0,
                                                    const float* __restrict__ W1,
                                                    const float* __restrict__ W2,
                                                    const float* __restrict__ Wfc,
                                                    __hip_bfloat16* __restrict__ CT,
                                                    int E, int NBC) {
    __shared__ int lcnt[MAXNBC];
    __shared__ int gbase_s[MAXNBC];
    int base = blockIdx.x * CHUNK;
    for (int i = threadIdx.x; i < NBC; i += 256) lcnt[i] = 0;
    __syncthreads();
    int myc[CHUNK / 256];
    #pragma unroll
    for (int q = 0; q < CHUNK / 256; ++q) {
        int e = base + q * 256 + threadIdx.x;
        int c = (e < E) ? ei[E + e] : -1;
        myc[q] = c;
        if (c >= 0) atomicAdd(&lcnt[c >> 8], 1);
    }
    __syncthreads();
    for (int f = threadIdx.x; f < NBC; f += 256) {
        int n = lcnt[f];
        gbase_s[f] = (n > 0) ? (f * SLACKC + atomicAdd(&gcur[f], n)) : 0;
    }
    __syncthreads();
    #pragma unroll
    for (int q = 0; q < CHUNK / 256; ++q) {
        int c = myc[q];
        if (c >= 0) {
            int e = base + q * 256 + threadIdx.x;
            unsigned r = (unsigned)ei[e];
            int p = atomicAdd(&gbase_s[c >> 8], 1);
            if (p < ((c >> 8) + 1) * SLACKC)   // overflow guard (P ~ 0)
                gsorted[p] = ((unsigned)c << 16) | r;
        }
    }
    // folded-weight compute (64 blocks x 256 threads = 16384 entries)
    if (blockIdx.x < 64) {
        int t = blockIdx.x * 256 + threadIdx.x;
        int n = t >> 7;
        int i = t & 127;
        float a = 0.f;
        if (n < 64) {
            for (int k = 0; k < 128; ++k)
                a += Wfc[n * 384 + k] * W0[k * N_IN + i];
        } else {
            int o = n - 64;
            for (int k = 0; k < 128; ++k)
                a += Wfc[o * 384 + 128 + k] * W1[k * N_IN + i]
                   + Wfc[o * 384 + 256 + k] * W2[k * N_IN + i];
        }
        CT[t] = __float2bfloat16(a);
    }
}

// Fused kernel. Blocks [0,NBC): per-coarse-bucket counting sort -> exact CSR
// (srow u16, offs/cnt/dis per node); edges staged in LDS; int LDS atomics only
// (f32 LDS atomicAdd is a CAS loop -- R5 lesson). Blocks [NBC,...): MFMA gemm
// out = x@C0^T, z8 = fp8(x@C12^T) UNSCALED (dis applied per-edge in gather):
// fp8 makes a z row exactly one 64B line -> halves gather's L2-miss volume.
__global__ __launch_bounds__(256) void sortgemm_kernel(
        const int* __restrict__ gcur,
        const unsigned* __restrict__ gsorted,
        unsigned short* __restrict__ srow,
        int* __restrict__ offs,
        int* __restrict__ cnt,
        float* __restrict__ dis,
        const float* __restrict__ x,
        const __hip_bfloat16* __restrict__ CT,
        float* __restrict__ out,
        unsigned char* __restrict__ z8,
        int N, int NBC) {
    __shared__ __align__(16) char smem[(64 + 128) * PADR * 2];   // 52224 B union
    int tid = threadIdx.x;

    if (blockIdx.x < NBC) {
        // ---------------- sort partition ----------------
        unsigned* ev = (unsigned*)smem;               // up to SLACKC edges (20KB)
        int* c256 = (int*)(smem + SLACKC * 4);        // 256 counts
        int* cur  = c256 + 256;                       // 256 cursors
        int* ts   = cur + 256;                        // 256 scan temp
        int f = blockIdx.x;
        int lo = f * SLACKC;
        int m = min(gcur[f], SLACKC);                 // gcur is relative count
        for (int i = tid; i < m; i += 256) ev[i] = gsorted[lo + i];
        c256[tid] = 0;
        __syncthreads();
        for (int i = tid; i < m; i += 256)
            atomicAdd(&c256[(ev[i] >> 16) & (CFB - 1)], 1);
        __syncthreads();
        int v = c256[tid];
        int xx = v;
        ts[tid] = xx;
        __syncthreads();
        for (int off = 1; off < 256; off <<= 1) {
            int t2 = (tid >= off) ? ts[tid - off] : 0;
            __syncthreads();
            xx += t2; ts[tid] = xx;
            __syncthreads();
        }
        int b = xx - v;          // exclusive prefix
        cur[tid] = b;
        int node = f * CFB + tid;
        if (node < N) {
            offs[node] = lo + b;
            cnt[node] = v;
            dis[node] = v > 0 ? rsqrtf((float)v) : 0.f;
        }
        __syncthreads();
        for (int i = tid; i < m; i += 256) {
            unsigned val = ev[i];
            int cl = (val >> 16) & (CFB - 1);
            int p = atomicAdd(&cur[cl], 1);
            srow[lo + p] = (unsigned short)(val & 0xffffu);
        }
        return;
    }

    // ---------------- gemm partition ----------------
    unsigned short* xs = (unsigned short*)smem;          // 64 x PADR
    unsigned short* Bs = xs + 64 * PADR;                 // 128 x PADR
    int base = (blockIdx.x - NBC) * 64;

    {   // stage x -> bf16 LDS
        int row = tid >> 2;
        int colq = (tid & 3) * 32;
        int node = base + row;
        unsigned tmp[16];
        if (node < N) {
            const float4* src = (const float4*)(x + (size_t)node * N_IN + colq);
            #pragma unroll
            for (int q = 0; q < 8; ++q) {
                float4 v = src[q];
                tmp[q * 2]     = pack_bf16(v.x, v.y);
                tmp[q * 2 + 1] = pack_bf16(v.z, v.w);
            }
        } else {
            #pragma unroll
            for (int q = 0; q < 16; ++q) tmp[q] = 0u;
        }
        unsigned* dst = (unsigned*)(xs + row * PADR + colq);
        #pragma unroll
        for (int q = 0; q < 16; ++q) dst[q] = tmp[q];
    }
    {   // stage CT -> LDS
        const unsigned* src = (const unsigned*)CT;
        for (int c = tid; c < 8192; c += 256) {
            int row = c >> 6;
            int col = (c & 63) * 2;
            *(unsigned*)(Bs + row * PADR + col) = src[c];
        }
    }
    __syncthreads();

    int wave = tid >> 6, lane = tid & 63;
    int wm = wave & 1, wn = wave >> 1;
    int quad = lane >> 4, l16 = lane & 15;

    floatx4 acc[2][4];
    #pragma unroll
    for (int mt = 0; mt < 2; ++mt)
        #pragma unroll
        for (int nt = 0; nt < 4; ++nt)
            acc[mt][nt] = (floatx4){0.f, 0.f, 0.f, 0.f};

    #pragma unroll
    for (int kc = 0; kc < 4; ++kc) {
        int kof = kc * 32 + quad * 8;
        short8 afr[2], bfr[4];
        #pragma unroll
        for (int mt = 0; mt < 2; ++mt)
            afr[mt] = *(const short8*)(xs + (wm * 32 + mt * 16 + l16) * PADR + kof);
        #pragma unroll
        for (int nt = 0; nt < 4; ++nt)
            bfr[nt] = *(const short8*)(Bs + (wn * 64 + nt * 16 + l16) * PADR + kof);
        #pragma unroll
        for (int mt = 0; mt < 2; ++mt)
            #pragma unroll
            for (int nt = 0; nt < 4; ++nt)
                acc[mt][nt] = __builtin_amdgcn_mfma_f32_16x16x32_bf16(
                    afr[mt], bfr[nt], acc[mt][nt], 0, 0, 0);
    }

    #pragma unroll
    for (int mt = 0; mt < 2; ++mt) {
        #pragma unroll
        for (int reg = 0; reg < 4; ++reg) {
            int node = base + wm * 32 + mt * 16 + quad * 4 + reg;
            if (node >= N) continue;
            if (wn == 0) {
                #pragma unroll
                for (int nt = 0; nt < 4; ++nt)
                    out[(size_t)node * N_OUT + nt * 16 + l16] = acc[mt][nt][reg];
            } else {
                #pragma unroll
                for (int nt = 0; nt < 4; ++nt)
                    z8[((size_t)node << 6) + nt * 16 + l16] = fp8b(acc[mt][nt][reg]);
            }
        }
    }
}

// One wave per dest node, register acc, no atomics. 8 edge-slots x 8 lanes;
// uint2/lane over fp8 rows: one 64B line per edge. dis[r] gathered with the
// indices (200KB, L2-resident) and shfl-broadcast; dis[c] applied at the end.
__global__ __launch_bounds__(256) void gather_kernel(
        const int* __restrict__ offs, const int* __restrict__ cnt,
        const unsigned short* __restrict__ srow, const unsigned char* __restrict__ z8,
        const float* __restrict__ dis, float* __restrict__ out, int N) {
    int node = blockIdx.x * 4 + (threadIdx.x >> 6);
    if (node >= N) return;
    int lane = threadIdx.x & 63;
    int sub  = lane >> 3;        // edge slot 0..7
    int jj   = lane & 7;         // byte-chunk index: dims 8jj..8jj+7
    int start = offs[node];
    int deg   = cnt[node];
    float a[8] = {0.f, 0.f, 0.f, 0.f, 0.f, 0.f, 0.f, 0.f};
    for (int k0 = 0; k0 < deg; k0 += 64) {
        int m = min(64, deg - k0);
        int idx = 0; float dv = 0.f;
        if (lane < m) {
            idx = (int)srow[start + k0 + lane];   // coalesced u16
            dv = dis[idx];                        // L2-resident random 4B
        }
        for (int kk = 0; kk < m; kk += 16) {
            int s0 = kk + sub, s1 = kk + 8 + sub;
            int r0 = __shfl(idx, s0); float d0 = __shfl(dv, s0);
            int r1 = __shfl(idx, s1); float d1 = __shfl(dv, s1);
            uint2 u0 = make_uint2(0u, 0u), u1 = make_uint2(0u, 0u);
            if (s0 < m) u0 = *(const uint2*)(z8 + ((size_t)r0 << 6) + jj * 8);
            if (s1 < m) u1 = *(const uint2*)(z8 + ((size_t)r1 << 6) + jj * 8);
            floatx2 p00 = __builtin_amdgcn_cvt_pk_f32_fp8(u0.x, false);
            floatx2 p01 = __builtin_amdgcn_cvt_pk_f32_fp8(u0.x, true);
            floatx2 p02 = __builtin_amdgcn_cvt_pk_f32_fp8(u0.y, false);
            floatx2 p03 = __builtin_amdgcn_cvt_pk_f32_fp8(u0.y, true);
            floatx2 p10 = __builtin_amdgcn_cvt_pk_f32_fp8(u1.x, false);
            floatx2 p11 = __builtin_amdgcn_cvt_pk_f32_fp8(u1.x, true);
            floatx2 p12 = __builtin_amdgcn_cvt_pk_f32_fp8(u1.y, false);
            floatx2 p13 = __builtin_amdgcn_cvt_pk_f32_fp8(u1.y, true);
            a[0] += d0 * p00.x + d1 * p10.x;
            a[1] += d0 * p00.y + d1 * p10.y;
            a[2] += d0 * p01.x + d1 * p11.x;
            a[3] += d0 * p01.y + d1 * p11.y;
            a[4] += d0 * p02.x + d1 * p12.x;
            a[5] += d0 * p02.y + d1 * p12.y;
            a[6] += d0 * p03.x + d1 * p13.x;
            a[7] += d0 * p03.y + d1 * p13.y;
        }
    }
    #pragma unroll
    for (int q = 0; q < 8; ++q) {
        a[q] += __shfl_xor(a[q], 8);
        a[q] += __shfl_xor(a[q], 16);
        a[q] += __shfl_xor(a[q], 32);
    }
    if (lane < 8 && deg > 0) {
        float dn = dis[node];
        float4* op = (float4*)(out + ((size_t)node << 6) + jj * 8);
        float4 o0 = op[0], o1 = op[1];
        o0.x += dn * a[0]; o0.y += dn * a[1]; o0.z += dn * a[2]; o0.w += dn * a[3];
        o1.x += dn * a[4]; o1.y += dn * a[5]; o1.z += dn * a[6]; o1.w += dn * a[7];
        op[0] = o0; op[1] = o1;
    }
}

extern "C" void kernel_launch(void* const* d_in, const int* in_sizes, int n_in,
                              void* d_out, int out_size, void* d_ws, size_t ws_size,
                              hipStream_t stream) {
    const float* x   = (const float*)d_in[0];
    const int*   ei  = (const int*)d_in[1];
    const float* W0  = (const float*)d_in[2];
    const float* W1  = (const float*)d_in[3];
    const float* W2  = (const float*)d_in[4];
    const float* Wfc = (const float*)d_in[5];
    float* out = (float*)d_out;
    int N = in_sizes[0] / N_IN;
    int E = in_sizes[1] / 2;
    int NBC = (N + CFB - 1) / CFB;   // 196
    int GB  = (N + 63) / 64;         // gemm blocks (782)

    __hip_bfloat16* CT = (__hip_bfloat16*)d_ws;             // 16384 bf16 = 32 KB
    int*   cnt     = (int*)((char*)d_ws + 32768);           // N
    float* dis     = (float*)(cnt + N);                     // N
    int*   gcur    = (int*)(dis + N);                       // NBC (zeroed)
    int*   offs    = gcur + NBC;                            // N
    unsigned* gsorted = (unsigned*)(offs + N);              // NBC*SLACKC
    unsigned short* srow = (unsigned short*)(gsorted + (size_t)NBC * SLACKC);
    size_t zoff = ((size_t)(srow + (size_t)NBC * SLACKC) - (size_t)d_ws + 63) & ~(size_t)63;
    unsigned char* z8 = (unsigned char*)d_ws + zoff;        // N*64 fp8 (64B rows)

    hipMemsetAsync(gcur, 0, (size_t)NBC * sizeof(int), stream);
    fill_scatter<<<(E + CHUNK - 1) / CHUNK, 256, 0, stream>>>(ei, gcur, gsorted,
                                                              W0, W1, W2, Wfc, CT, E, NBC);
    sortgemm_kernel<<<NBC + GB, 256, 0, stream>>>(gcur, gsorted, srow, offs, cnt, dis,
                                                  x, CT, out, z8, N, NBC);
    gather_kernel<<<(N + 3) / 4, 256, 0, stream>>>(offs, cnt, srow, z8, dis, out, N);
}

// Round 14
// 136.642 us; speedup vs baseline: 2.6146x; 1.0572x over previous
//
#include <hip/hip_runtime.h>
#include <hip/hip_bf16.h>

#define N_IN  128
#define N_OUT 64
#define CFB    256          // nodes per coarse bucket (fill/sort granularity)
#define MAXNBC 200          // >= ceil(50000/256) = 196
#define SLACKC 5120         // slots per coarse bucket (mean 4096, +16 sigma)
#define CHUNK  4096         // edges per fill block (196 blocks; halves gcur contention vs 2048)
#define PADR   136          // LDS row pitch in bf16 (+8 pad -> 2-way banks, free)

typedef __attribute__((ext_vector_type(8))) short short8;
typedef __attribute__((ext_vector_type(4))) float floatx4;
typedef __attribute__((ext_vector_type(2))) float floatx2;

__device__ __forceinline__ unsigned pack_bf16(float a, float b) {
    __hip_bfloat16 ba = __float2bfloat16(a);
    __hip_bfloat16 bb = __float2bfloat16(b);
    unsigned short ua = *(unsigned short*)&ba;
    unsigned short ub = *(unsigned short*)&bb;
    return ((unsigned)ub << 16) | ua;
}
// f32 -> OCP e4m3 byte (gfx950 cvt_pk_fp8 is OCP-format)
__device__ __forceinline__ unsigned char fp8b(float v) {
    return (unsigned char)(__builtin_amdgcn_cvt_pk_fp8_f32(v, v, 0, false) & 0xff);
}

// Append edges into per-coarse-bucket slack regions (relative cursors; gcur
// zeroed by memset). Runs average CHUNK/NBC ~ 21 edges -> writes mostly cover
// cache lines (R4/R9 lesson). Blocks 0..63 also fold the weights into
// CT[128][128] bf16 (rows 0..63 = out cols; 64..127 = z cols) -- CT is only
// consumed by the NEXT dispatch, so overlapping it here is free.
__global__ __launch_bounds__(256) void fill_scatter(const int* __restrict__ ei,
                                                    int* __restrict__ gcur,
                                                    unsigned* __restrict__ gsorted,
                                                    const float* __restrict__ W0,
                                                    const float* __restrict__ W1,
                                                    const float* __restrict__ W2,
                                                    const float* __restrict__ Wfc,
                                                    __hip_bfloat16* __restrict__ CT,
                                                    int E, int NBC) {
    __shared__ int lcnt[MAXNBC];
    __shared__ int gbase_s[MAXNBC];
    int base = blockIdx.x * CHUNK;
    for (int i = threadIdx.x; i < NBC; i += 256) lcnt[i] = 0;
    __syncthreads();
    int myc[CHUNK / 256];
    #pragma unroll
    for (int q = 0; q < CHUNK / 256; ++q) {
        int e = base + q * 256 + threadIdx.x;
        int c = (e < E) ? ei[E + e] : -1;
        myc[q] = c;
        if (c >= 0) atomicAdd(&lcnt[c >> 8], 1);
    }
    __syncthreads();
    for (int f = threadIdx.x; f < NBC; f += 256) {
        int n = lcnt[f];
        gbase_s[f] = (n > 0) ? (f * SLACKC + atomicAdd(&gcur[f], n)) : 0;
    }
    __syncthreads();
    #pragma unroll
    for (int q = 0; q < CHUNK / 256; ++q) {
        int c = myc[q];
        if (c >= 0) {
            int e = base + q * 256 + threadIdx.x;
            unsigned r = (unsigned)ei[e];
            int p = atomicAdd(&gbase_s[c >> 8], 1);
            if (p < ((c >> 8) + 1) * SLACKC)   // overflow guard (P ~ 0)
                gsorted[p] = ((unsigned)c << 16) | r;
        }
    }
    // folded-weight compute (64 blocks x 256 threads = 16384 entries)
    if (blockIdx.x < 64) {
        int t = blockIdx.x * 256 + threadIdx.x;
        int n = t >> 7;
        int i = t & 127;
        float a = 0.f;
        if (n < 64) {
            for (int k = 0; k < 128; ++k)
                a += Wfc[n * 384 + k] * W0[k * N_IN + i];
        } else {
            int o = n - 64;
            for (int k = 0; k < 128; ++k)
                a += Wfc[o * 384 + 128 + k] * W1[k * N_IN + i]
                   + Wfc[o * 384 + 256 + k] * W2[k * N_IN + i];
        }
        CT[t] = __float2bfloat16(a);
    }
}

// Fused kernel. Blocks [0,NBC): per-coarse-bucket counting sort -> exact CSR
// (srow u16, offs/cnt/dis per node); edges staged in LDS; int LDS atomics only
// (f32 LDS atomicAdd is a CAS loop -- R5 lesson). Blocks [NBC,...): MFMA gemm
// out = x@C0^T, z8 = fp8(x@C12^T) UNSCALED (dis applied per-edge in gather).
__global__ __launch_bounds__(256) void sortgemm_kernel(
        const int* __restrict__ gcur,
        const unsigned* __restrict__ gsorted,
        unsigned short* __restrict__ srow,
        int* __restrict__ offs,
        int* __restrict__ cnt,
        float* __restrict__ dis,
        const float* __restrict__ x,
        const __hip_bfloat16* __restrict__ CT,
        float* __restrict__ out,
        unsigned char* __restrict__ z8,
        int N, int NBC) {
    __shared__ __align__(16) char smem[(64 + 128) * PADR * 2];   // 52224 B union
    int tid = threadIdx.x;

    if (blockIdx.x < NBC) {
        // ---------------- sort partition ----------------
        unsigned* ev = (unsigned*)smem;               // up to SLACKC edges (20KB)
        int* c256 = (int*)(smem + SLACKC * 4);        // 256 counts
        int* cur  = c256 + 256;                       // 256 cursors
        int* ts   = cur + 256;                        // 256 scan temp
        int f = blockIdx.x;
        int lo = f * SLACKC;
        int m = min(gcur[f], SLACKC);                 // gcur is relative count
        for (int i = tid; i < m; i += 256) ev[i] = gsorted[lo + i];
        c256[tid] = 0;
        __syncthreads();
        for (int i = tid; i < m; i += 256)
            atomicAdd(&c256[(ev[i] >> 16) & (CFB - 1)], 1);
        __syncthreads();
        int v = c256[tid];
        int xx = v;
        ts[tid] = xx;
        __syncthreads();
        for (int off = 1; off < 256; off <<= 1) {
            int t2 = (tid >= off) ? ts[tid - off] : 0;
            __syncthreads();
            xx += t2; ts[tid] = xx;
            __syncthreads();
        }
        int b = xx - v;          // exclusive prefix
        cur[tid] = b;
        int node = f * CFB + tid;
        if (node < N) {
            offs[node] = lo + b;
            cnt[node] = v;
            dis[node] = v > 0 ? rsqrtf((float)v) : 0.f;
        }
        __syncthreads();
        for (int i = tid; i < m; i += 256) {
            unsigned val = ev[i];
            int cl = (val >> 16) & (CFB - 1);
            int p = atomicAdd(&cur[cl], 1);
            srow[lo + p] = (unsigned short)(val & 0xffffu);
        }
        return;
    }

    // ---------------- gemm partition ----------------
    unsigned short* xs = (unsigned short*)smem;          // 64 x PADR
    unsigned short* Bs = xs + 64 * PADR;                 // 128 x PADR
    int base = (blockIdx.x - NBC) * 64;

    {   // stage x -> bf16 LDS
        int row = tid >> 2;
        int colq = (tid & 3) * 32;
        int node = base + row;
        unsigned tmp[16];
        if (node < N) {
            const float4* src = (const float4*)(x + (size_t)node * N_IN + colq);
            #pragma unroll
            for (int q = 0; q < 8; ++q) {
                float4 v = src[q];
                tmp[q * 2]     = pack_bf16(v.x, v.y);
                tmp[q * 2 + 1] = pack_bf16(v.z, v.w);
            }
        } else {
            #pragma unroll
            for (int q = 0; q < 16; ++q) tmp[q] = 0u;
        }
        unsigned* dst = (unsigned*)(xs + row * PADR + colq);
        #pragma unroll
        for (int q = 0; q < 16; ++q) dst[q] = tmp[q];
    }
    {   // stage CT -> LDS
        const unsigned* src = (const unsigned*)CT;
        for (int c = tid; c < 8192; c += 256) {
            int row = c >> 6;
            int col = (c & 63) * 2;
            *(unsigned*)(Bs + row * PADR + col) = src[c];
        }
    }
    __syncthreads();

    int wave = tid >> 6, lane = tid & 63;
    int wm = wave & 1, wn = wave >> 1;
    int quad = lane >> 4, l16 = lane & 15;

    floatx4 acc[2][4];
    #pragma unroll
    for (int mt = 0; mt < 2; ++mt)
        #pragma unroll
        for (int nt = 0; nt < 4; ++nt)
            acc[mt][nt] = (floatx4){0.f, 0.f, 0.f, 0.f};

    #pragma unroll
    for (int kc = 0; kc < 4; ++kc) {
        int kof = kc * 32 + quad * 8;
        short8 afr[2], bfr[4];
        #pragma unroll
        for (int mt = 0; mt < 2; ++mt)
            afr[mt] = *(const short8*)(xs + (wm * 32 + mt * 16 + l16) * PADR + kof);
        #pragma unroll
        for (int nt = 0; nt < 4; ++nt)
            bfr[nt] = *(const short8*)(Bs + (wn * 64 + nt * 16 + l16) * PADR + kof);
        #pragma unroll
        for (int mt = 0; mt < 2; ++mt)
            #pragma unroll
            for (int nt = 0; nt < 4; ++nt)
                acc[mt][nt] = __builtin_amdgcn_mfma_f32_16x16x32_bf16(
                    afr[mt], bfr[nt], acc[mt][nt], 0, 0, 0);
    }

    #pragma unroll
    for (int mt = 0; mt < 2; ++mt) {
        #pragma unroll
        for (int reg = 0; reg < 4; ++reg) {
            int node = base + wm * 32 + mt * 16 + quad * 4 + reg;
            if (node >= N) continue;
            if (wn == 0) {
                #pragma unroll
                for (int nt = 0; nt < 4; ++nt)
                    out[(size_t)node * N_OUT + nt * 16 + l16] = acc[mt][nt][reg];
            } else {
                #pragma unroll
                for (int nt = 0; nt < 4; ++nt)
                    z8[((size_t)node << 6) + nt * 16 + l16] = fp8b(acc[mt][nt][reg]);
            }
        }
    }
}

// TWO nodes per wave (32 lanes each: 4 edge-slots x 8 dim-lanes), register
// acc, no atomics. Inner loop fully unrolled over a 32-edge chunk with
// exec-masked loads: 8 z8-line loads issued back-to-back per wave before
// first use (vs 2 in the 1-node/wave form) -- attacks the short-wave latency
// bound (mean deg = 16). dis[r] staged with the indices; dis[c] at the end.
__global__ __launch_bounds__(256) void gather_kernel(
        const int* __restrict__ offs, const int* __restrict__ cnt,
        const unsigned short* __restrict__ srow, const unsigned char* __restrict__ z8,
        const float* __restrict__ dis, float* __restrict__ out, int N) {
    int lane = threadIdx.x & 63;
    int half = lane >> 5;        // which node of the pair
    int hl   = lane & 31;        // lane within half
    int sub  = hl >> 3;          // edge slot 0..3
    int jj   = hl & 7;           // byte-chunk: dims 8jj..8jj+7
    int node = blockIdx.x * 8 + (threadIdx.x >> 6) * 2 + half;
    int start = 0, deg = 0;
    if (node < N) { start = offs[node]; deg = cnt[node]; }
    float a[8] = {0.f, 0.f, 0.f, 0.f, 0.f, 0.f, 0.f, 0.f};
    for (int k0 = 0; k0 < deg; k0 += 32) {
        int m = min(32, deg - k0);               // per-half edge count (wave-divergent ok)
        int idx = 0; float dv = 0.f;
        if (hl < m) {
            idx = (int)srow[start + k0 + hl];    // coalesced u16, both halves at once
            dv = dis[idx];                       // L2-resident random 4B
        }
        #pragma unroll
        for (int it = 0; it < 4; ++it) {
            int s0 = it * 8 + sub, s1 = it * 8 + 4 + sub;
            int src0 = (lane & 32) | s0, src1 = (lane & 32) | s1;
            int r0 = __shfl(idx, src0); float d0 = __shfl(dv, src0);
            int r1 = __shfl(idx, src1); float d1 = __shfl(dv, src1);
            uint2 u0 = make_uint2(0u, 0u), u1 = make_uint2(0u, 0u);
            if (s0 < m) u0 = *(const uint2*)(z8 + ((size_t)r0 << 6) + jj * 8);
            if (s1 < m) u1 = *(const uint2*)(z8 + ((size_t)r1 << 6) + jj * 8);
            floatx2 p00 = __builtin_amdgcn_cvt_pk_f32_fp8(u0.x, false);
            floatx2 p01 = __builtin_amdgcn_cvt_pk_f32_fp8(u0.x, true);
            floatx2 p02 = __builtin_amdgcn_cvt_pk_f32_fp8(u0.y, false);
            floatx2 p03 = __builtin_amdgcn_cvt_pk_f32_fp8(u0.y, true);
            floatx2 p10 = __builtin_amdgcn_cvt_pk_f32_fp8(u1.x, false);
            floatx2 p11 = __builtin_amdgcn_cvt_pk_f32_fp8(u1.x, true);
            floatx2 p12 = __builtin_amdgcn_cvt_pk_f32_fp8(u1.y, false);
            floatx2 p13 = __builtin_amdgcn_cvt_pk_f32_fp8(u1.y, true);
            a[0] += d0 * p00.x + d1 * p10.x;
            a[1] += d0 * p00.y + d1 * p10.y;
            a[2] += d0 * p01.x + d1 * p11.x;
            a[3] += d0 * p01.y + d1 * p11.y;
            a[4] += d0 * p02.x + d1 * p12.x;
            a[5] += d0 * p02.y + d1 * p12.y;
            a[6] += d0 * p03.x + d1 * p13.x;
            a[7] += d0 * p03.y + d1 * p13.y;
        }
    }
    // reduce the 4 edge slots within each 32-lane half
    #pragma unroll
    for (int q = 0; q < 8; ++q) {
        a[q] += __shfl_xor(a[q], 8);
        a[q] += __shfl_xor(a[q], 16);
    }
    if (hl < 8 && deg > 0) {
        float dn = dis[node];
        float4* op = (float4*)(out + ((size_t)node << 6) + jj * 8);
        float4 o0 = op[0], o1 = op[1];
        o0.x += dn * a[0]; o0.y += dn * a[1]; o0.z += dn * a[2]; o0.w += dn * a[3];
        o1.x += dn * a[4]; o1.y += dn * a[5]; o1.z += dn * a[6]; o1.w += dn * a[7];
        op[0] = o0; op[1] = o1;
    }
}

extern "C" void kernel_launch(void* const* d_in, const int* in_sizes, int n_in,
                              void* d_out, int out_size, void* d_ws, size_t ws_size,
                              hipStream_t stream) {
    const float* x   = (const float*)d_in[0];
    const int*   ei  = (const int*)d_in[1];
    const float* W0  = (const float*)d_in[2];
    const float* W1  = (const float*)d_in[3];
    const float* W2  = (const float*)d_in[4];
    const float* Wfc = (const float*)d_in[5];
    float* out = (float*)d_out;
    int N = in_sizes[0] / N_IN;
    int E = in_sizes[1] / 2;
    int NBC = (N + CFB - 1) / CFB;   // 196
    int GB  = (N + 63) / 64;         // gemm blocks (782)

    __hip_bfloat16* CT = (__hip_bfloat16*)d_ws;             // 16384 bf16 = 32 KB
    int*   cnt     = (int*)((char*)d_ws + 32768);           // N
    float* dis     = (float*)(cnt + N);                     // N
    int*   gcur    = (int*)(dis + N);                       // NBC (zeroed)
    int*   offs    = gcur + NBC;                            // N
    unsigned* gsorted = (unsigned*)(offs + N);              // NBC*SLACKC
    unsigned short* srow = (unsigned short*)(gsorted + (size_t)NBC * SLACKC);
    size_t zoff = ((size_t)(srow + (size_t)NBC * SLACKC) - (size_t)d_ws + 63) & ~(size_t)63;
    unsigned char* z8 = (unsigned char*)d_ws + zoff;        // N*64 fp8 (64B rows)

    hipMemsetAsync(gcur, 0, (size_t)NBC * sizeof(int), stream);
    fill_scatter<<<(E + CHUNK - 1) / CHUNK, 256, 0, stream>>>(ei, gcur, gsorted,
                                                              W0, W1, W2, Wfc, CT, E, NBC);
    sortgemm_kernel<<<NBC + GB, 256, 0, stream>>>(gcur, gsorted, srow, offs, cnt, dis,
                                                  x, CT, out, z8, N, NBC);
    gather_kernel<<<(N + 7) / 8, 256, 0, stream>>>(offs, cnt, srow, z8, dis, out, N);
}

// Round 15
// 134.009 us; speedup vs baseline: 2.6659x; 1.0197x over previous
//
#include <hip/hip_runtime.h>
#include <hip/hip_bf16.h>

#define N_IN  128
#define N_OUT 64
#define CFB    256          // nodes per coarse bucket (fill/sort granularity)
#define MAXNBC 200          // >= ceil(50000/256) = 196
#define SLACKC 5120         // slots per coarse bucket (mean 4096, +16 sigma)
#define CHUNK  4096         // edges per fill block (196 blocks)
#define PADR   136          // LDS row pitch in bf16 (+8 pad -> 2-way banks, free)

typedef __attribute__((ext_vector_type(8))) short short8;
typedef __attribute__((ext_vector_type(4))) float floatx4;
typedef __attribute__((ext_vector_type(2))) float floatx2;

__device__ __forceinline__ unsigned pack_bf16(float a, float b) {
    __hip_bfloat16 ba = __float2bfloat16(a);
    __hip_bfloat16 bb = __float2bfloat16(b);
    unsigned short ua = *(unsigned short*)&ba;
    unsigned short ub = *(unsigned short*)&bb;
    return ((unsigned)ub << 16) | ua;
}
// f32 -> OCP e4m3 byte (gfx950 cvt_pk_fp8 is OCP-format)
__device__ __forceinline__ unsigned char fp8b(float v) {
    return (unsigned char)(__builtin_amdgcn_cvt_pk_fp8_f32(v, v, 0, false) & 0xff);
}

// Append edges into per-coarse-bucket slack regions (relative cursors; gcur
// zeroed by memset). Runs average CHUNK/NBC ~ 21 edges -> writes mostly cover
// cache lines (R4/R9 lesson). Blocks 0..63 also fold the weights into
// CT[128][128] bf16 (rows 0..63 = out cols; 64..127 = z cols) -- CT is only
// consumed by the NEXT dispatch, so overlapping it here is free.
__global__ __launch_bounds__(256) void fill_scatter(const int* __restrict__ ei,
                                                    int* __restrict__ gcur,
                                                    unsigned* __restrict__ gsorted,
                                                    const float* __restrict__ W0,
                                                    const float* __restrict__ W1,
                                                    const float* __restrict__ W2,
                                                    const float* __restrict__ Wfc,
                                                    __hip_bfloat16* __restrict__ CT,
                                                    int E, int NBC) {
    __shared__ int lcnt[MAXNBC];
    __shared__ int gbase_s[MAXNBC];
    int base = blockIdx.x * CHUNK;
    for (int i = threadIdx.x; i < NBC; i += 256) lcnt[i] = 0;
    __syncthreads();
    int myc[CHUNK / 256];
    #pragma unroll
    for (int q = 0; q < CHUNK / 256; ++q) {
        int e = base + q * 256 + threadIdx.x;
        int c = (e < E) ? ei[E + e] : -1;
        myc[q] = c;
        if (c >= 0) atomicAdd(&lcnt[c >> 8], 1);
    }
    __syncthreads();
    for (int f = threadIdx.x; f < NBC; f += 256) {
        int n = lcnt[f];
        gbase_s[f] = (n > 0) ? (f * SLACKC + atomicAdd(&gcur[f], n)) : 0;
    }
    __syncthreads();
    #pragma unroll
    for (int q = 0; q < CHUNK / 256; ++q) {
        int c = myc[q];
        if (c >= 0) {
            int e = base + q * 256 + threadIdx.x;
            unsigned r = (unsigned)ei[e];
            int p = atomicAdd(&gbase_s[c >> 8], 1);
            if (p < ((c >> 8) + 1) * SLACKC)   // overflow guard (P ~ 0)
                gsorted[p] = ((unsigned)c << 16) | r;
        }
    }
    // folded-weight compute (64 blocks x 256 threads = 16384 entries)
    if (blockIdx.x < 64) {
        int t = blockIdx.x * 256 + threadIdx.x;
        int n = t >> 7;
        int i = t & 127;
        float a = 0.f;
        if (n < 64) {
            for (int k = 0; k < 128; ++k)
                a += Wfc[n * 384 + k] * W0[k * N_IN + i];
        } else {
            int o = n - 64;
            for (int k = 0; k < 128; ++k)
                a += Wfc[o * 384 + 128 + k] * W1[k * N_IN + i]
                   + Wfc[o * 384 + 256 + k] * W2[k * N_IN + i];
        }
        CT[t] = __float2bfloat16(a);
    }
}

// Fused kernel. Blocks [0,NBC): per-coarse-bucket counting sort -> exact CSR
// (srow u16, offs/cnt/dis per node); edges staged in LDS; int LDS atomics only
// (f32 LDS atomicAdd is a CAS loop -- R5 lesson). Blocks [NBC,...): MFMA gemm
// out = x@C0^T, z8 = fp8(x@C12^T) UNSCALED (dis applied per-edge in gather).
__global__ __launch_bounds__(256) void sortgemm_kernel(
        const int* __restrict__ gcur,
        const unsigned* __restrict__ gsorted,
        unsigned short* __restrict__ srow,
        int* __restrict__ offs,
        int* __restrict__ cnt,
        float* __restrict__ dis,
        const float* __restrict__ x,
        const __hip_bfloat16* __restrict__ CT,
        float* __restrict__ out,
        unsigned char* __restrict__ z8,
        int N, int NBC) {
    __shared__ __align__(16) char smem[(64 + 128) * PADR * 2];   // 52224 B union
    int tid = threadIdx.x;

    if (blockIdx.x < NBC) {
        // ---------------- sort partition ----------------
        unsigned* ev = (unsigned*)smem;               // up to SLACKC edges (20KB)
        int* c256 = (int*)(smem + SLACKC * 4);        // 256 counts
        int* cur  = c256 + 256;                       // 256 cursors
        int* ts   = cur + 256;                        // 256 scan temp
        int f = blockIdx.x;
        int lo = f * SLACKC;
        int m = min(gcur[f], SLACKC);                 // gcur is relative count
        for (int i = tid; i < m; i += 256) ev[i] = gsorted[lo + i];
        c256[tid] = 0;
        __syncthreads();
        for (int i = tid; i < m; i += 256)
            atomicAdd(&c256[(ev[i] >> 16) & (CFB - 1)], 1);
        __syncthreads();
        int v = c256[tid];
        int xx = v;
        ts[tid] = xx;
        __syncthreads();
        for (int off = 1; off < 256; off <<= 1) {
            int t2 = (tid >= off) ? ts[tid - off] : 0;
            __syncthreads();
            xx += t2; ts[tid] = xx;
            __syncthreads();
        }
        int b = xx - v;          // exclusive prefix
        cur[tid] = b;
        int node = f * CFB + tid;
        if (node < N) {
            offs[node] = lo + b;
            cnt[node] = v;
            dis[node] = v > 0 ? rsqrtf((float)v) : 0.f;
        }
        __syncthreads();
        for (int i = tid; i < m; i += 256) {
            unsigned val = ev[i];
            int cl = (val >> 16) & (CFB - 1);
            int p = atomicAdd(&cur[cl], 1);
            srow[lo + p] = (unsigned short)(val & 0xffffu);
        }
        return;
    }

    // ---------------- gemm partition ----------------
    unsigned short* xs = (unsigned short*)smem;          // 64 x PADR
    unsigned short* Bs = xs + 64 * PADR;                 // 128 x PADR
    int base = (blockIdx.x - NBC) * 64;

    {   // stage x -> bf16 LDS
        int row = tid >> 2;
        int colq = (tid & 3) * 32;
        int node = base + row;
        unsigned tmp[16];
        if (node < N) {
            const float4* src = (const float4*)(x + (size_t)node * N_IN + colq);
            #pragma unroll
            for (int q = 0; q < 8; ++q) {
                float4 v = src[q];
                tmp[q * 2]     = pack_bf16(v.x, v.y);
                tmp[q * 2 + 1] = pack_bf16(v.z, v.w);
            }
        } else {
            #pragma unroll
            for (int q = 0; q < 16; ++q) tmp[q] = 0u;
        }
        unsigned* dst = (unsigned*)(xs + row * PADR + colq);
        #pragma unroll
        for (int q = 0; q < 16; ++q) dst[q] = tmp[q];
    }
    {   // stage CT -> LDS
        const unsigned* src = (const unsigned*)CT;
        for (int c = tid; c < 8192; c += 256) {
            int row = c >> 6;
            int col = (c & 63) * 2;
            *(unsigned*)(Bs + row * PADR + col) = src[c];
        }
    }
    __syncthreads();

    int wave = tid >> 6, lane = tid & 63;
    int wm = wave & 1, wn = wave >> 1;
    int quad = lane >> 4, l16 = lane & 15;

    floatx4 acc[2][4];
    #pragma unroll
    for (int mt = 0; mt < 2; ++mt)
        #pragma unroll
        for (int nt = 0; nt < 4; ++nt)
            acc[mt][nt] = (floatx4){0.f, 0.f, 0.f, 0.f};

    #pragma unroll
    for (int kc = 0; kc < 4; ++kc) {
        int kof = kc * 32 + quad * 8;
        short8 afr[2], bfr[4];
        #pragma unroll
        for (int mt = 0; mt < 2; ++mt)
            afr[mt] = *(const short8*)(xs + (wm * 32 + mt * 16 + l16) * PADR + kof);
        #pragma unroll
        for (int nt = 0; nt < 4; ++nt)
            bfr[nt] = *(const short8*)(Bs + (wn * 64 + nt * 16 + l16) * PADR + kof);
        #pragma unroll
        for (int mt = 0; mt < 2; ++mt)
            #pragma unroll
            for (int nt = 0; nt < 4; ++nt)
                acc[mt][nt] = __builtin_amdgcn_mfma_f32_16x16x32_bf16(
                    afr[mt], bfr[nt], acc[mt][nt], 0, 0, 0);
    }

    #pragma unroll
    for (int mt = 0; mt < 2; ++mt) {
        #pragma unroll
        for (int reg = 0; reg < 4; ++reg) {
            int node = base + wm * 32 + mt * 16 + quad * 4 + reg;
            if (node >= N) continue;
            if (wn == 0) {
                #pragma unroll
                for (int nt = 0; nt < 4; ++nt)
                    out[(size_t)node * N_OUT + nt * 16 + l16] = acc[mt][nt][reg];
            } else {
                #pragma unroll
                for (int nt = 0; nt < 4; ++nt)
                    z8[((size_t)node << 6) + nt * 16 + l16] = fp8b(acc[mt][nt][reg]);
            }
        }
    }
}

// FOUR nodes per wave (16 lanes each: 2 edge-slots x 8 dim-lanes), register
// acc, no atomics. Chunk = 16 edges = mean degree: full lane utilization on
// the index stage for the common case, all 8 unrolled iterations active,
// each load instruction covers 8 distinct z8 rows (512B). dis[r] staged with
// the indices (L2-resident); dis[c] applied at the end.
__global__ __launch_bounds__(256) void gather_kernel(
        const int* __restrict__ offs, const int* __restrict__ cnt,
        const unsigned short* __restrict__ srow, const unsigned char* __restrict__ z8,
        const float* __restrict__ dis, float* __restrict__ out, int N) {
    int lane = threadIdx.x & 63;
    int quarter = lane >> 4;     // which node of the four
    int ql   = lane & 15;        // lane within quarter
    int sub  = ql >> 3;          // edge slot 0..1
    int jj   = ql & 7;           // byte-chunk: dims 8jj..8jj+7
    int node = blockIdx.x * 16 + (threadIdx.x >> 6) * 4 + quarter;
    int start = 0, deg = 0;
    if (node < N) { start = offs[node]; deg = cnt[node]; }
    float a[8] = {0.f, 0.f, 0.f, 0.f, 0.f, 0.f, 0.f, 0.f};
    for (int k0 = 0; k0 < deg; k0 += 16) {
        int m = min(16, deg - k0);               // per-quarter edge count
        int idx = 0; float dv = 0.f;
        if (ql < m) {
            idx = (int)srow[start + k0 + ql];    // coalesced u16, all quarters at once
            dv = dis[idx];                       // L2-resident random 4B
        }
        #pragma unroll
        for (int it = 0; it < 8; ++it) {
            int s0 = it * 2 + sub;
            int src0 = (lane & 48) | s0;         // stay within this quarter
            int r0 = __shfl(idx, src0); float d0 = __shfl(dv, src0);
            uint2 u0 = make_uint2(0u, 0u);
            if (s0 < m) u0 = *(const uint2*)(z8 + ((size_t)r0 << 6) + jj * 8);
            floatx2 p00 = __builtin_amdgcn_cvt_pk_f32_fp8(u0.x, false);
            floatx2 p01 = __builtin_amdgcn_cvt_pk_f32_fp8(u0.x, true);
            floatx2 p02 = __builtin_amdgcn_cvt_pk_f32_fp8(u0.y, false);
            floatx2 p03 = __builtin_amdgcn_cvt_pk_f32_fp8(u0.y, true);
            a[0] += d0 * p00.x;
            a[1] += d0 * p00.y;
            a[2] += d0 * p01.x;
            a[3] += d0 * p01.y;
            a[4] += d0 * p02.x;
            a[5] += d0 * p02.y;
            a[6] += d0 * p03.x;
            a[7] += d0 * p03.y;
        }
    }
    // merge the 2 edge slots within each 16-lane quarter
    #pragma unroll
    for (int q = 0; q < 8; ++q)
        a[q] += __shfl_xor(a[q], 8);
    if (ql < 8 && deg > 0) {
        float dn = dis[node];
        float4* op = (float4*)(out + ((size_t)node << 6) + jj * 8);
        float4 o0 = op[0], o1 = op[1];
        o0.x += dn * a[0]; o0.y += dn * a[1]; o0.z += dn * a[2]; o0.w += dn * a[3];
        o1.x += dn * a[4]; o1.y += dn * a[5]; o1.z += dn * a[6]; o1.w += dn * a[7];
        op[0] = o0; op[1] = o1;
    }
}

extern "C" void kernel_launch(void* const* d_in, const int* in_sizes, int n_in,
                              void* d_out, int out_size, void* d_ws, size_t ws_size,
                              hipStream_t stream) {
    const float* x   = (const float*)d_in[0];
    const int*   ei  = (const int*)d_in[1];
    const float* W0  = (const float*)d_in[2];
    const float* W1  = (const float*)d_in[3];
    const float* W2  = (const float*)d_in[4];
    const float* Wfc = (const float*)d_in[5];
    float* out = (float*)d_out;
    int N = in_sizes[0] / N_IN;
    int E = in_sizes[1] / 2;
    int NBC = (N + CFB - 1) / CFB;   // 196
    int GB  = (N + 63) / 64;         // gemm blocks (782)

    __hip_bfloat16* CT = (__hip_bfloat16*)d_ws;             // 16384 bf16 = 32 KB
    int*   cnt     = (int*)((char*)d_ws + 32768);           // N
    float* dis     = (float*)(cnt + N);                     // N
    int*   gcur    = (int*)(dis + N);                       // NBC (zeroed)
    int*   offs    = gcur + NBC;                            // N
    unsigned* gsorted = (unsigned*)(offs + N);              // NBC*SLACKC
    unsigned short* srow = (unsigned short*)(gsorted + (size_t)NBC * SLACKC);
    size_t zoff = ((size_t)(srow + (size_t)NBC * SLACKC) - (size_t)d_ws + 63) & ~(size_t)63;
    unsigned char* z8 = (unsigned char*)d_ws + zoff;        // N*64 fp8 (64B rows)

    hipMemsetAsync(gcur, 0, (size_t)NBC * sizeof(int), stream);
    fill_scatter<<<(E + CHUNK - 1) / CHUNK, 256, 0, stream>>>(ei, gcur, gsorted,
                                                              W0, W1, W2, Wfc, CT, E, NBC);
    sortgemm_kernel<<<NBC + GB, 256, 0, stream>>>(gcur, gsorted, srow, offs, cnt, dis,
                                                  x, CT, out, z8, N, NBC);
    gather_kernel<<<(N + 15) / 16, 256, 0, stream>>>(offs, cnt, srow, z8, dis, out, N);
}